// Round 1
// baseline (893.607 us; speedup 1.0000x reference)
//
#include <hip/hip_runtime.h>
#include <stdint.h>

// B=256, K=36 -> 9216 rows; D=2048, E=1024, P=5.
// Pipeline (all bf16 MFMA GEMMs, fp32 accumulate, fp32 epilogue math):
//   prep: transpose+cvt weights to B^T bf16; cvt images to bf16
//   G1: x @ [gate_w1|node_w1] (N=4096) + bias + 0.1*bbox-rank5-corr, relu -> Hcat bf16
//   gate2: m = sigmoid(Hcat[:, :2048] . gate_w2 + gate_b2)
//   G2: Hcat[:,2048:] @ node_w2 + node_b2 -> V bf16
//   agg: top-P(ballot) gather, out=l2norm(sum m*v), imgs=images+out -> bf16
//   G3: imgs @ map_w1 + map_b1, relu -> H3 bf16
//   G4: H3 @ map_w2 + map_b2 -> emb fp32 ; final l2norm -> d_out

typedef unsigned short ushort_t;
typedef unsigned int uint32;
typedef __bf16 bf16x8 __attribute__((ext_vector_type(8)));
typedef float f32x4 __attribute__((ext_vector_type(4)));

__device__ __forceinline__ ushort_t f2bf(float f) {
  uint32 u = __float_as_uint(f);
  u += 0x7fffu + ((u >> 16) & 1u);   // RNE
  return (ushort_t)(u >> 16);
}
__device__ __forceinline__ float bflo(uint32 u) { return __uint_as_float(u << 16); }
__device__ __forceinline__ float bfhi(uint32 u) { return __uint_as_float(u & 0xffff0000u); }

__device__ __forceinline__ void gl_lds16(const void* g, void* l) {
  // width-16 async global->LDS; LDS dest is wave-uniform base + lane*16
  __builtin_amdgcn_global_load_lds(
      (__attribute__((address_space(1))) void*)(void*)g,
      (__attribute__((address_space(3))) void*)l, 16, 0, 0);
}

__device__ __forceinline__ float blk_sum(float v, float* sred) {
#pragma unroll
  for (int o = 32; o > 0; o >>= 1) v += __shfl_down(v, o, 64);
  const int w = threadIdx.x >> 6;
  if ((threadIdx.x & 63) == 0) sred[w] = v;
  __syncthreads();
  return sred[0] + sred[1] + sred[2] + sred[3];
}

// ---------- transpose + fp32->bf16: src (RK x CN) -> dst (CN x RK) ----------
__global__ __launch_bounds__(256) void transpose_bf16(
    const float* __restrict__ src, ushort_t* __restrict__ dst, int RK, int CN) {
  __shared__ float tile[32][33];
  const int bx = blockIdx.x;  // CN/32
  const int by = blockIdx.y;  // RK/32
  const int c = bx * 32 + threadIdx.x;
#pragma unroll
  for (int t = 0; t < 4; ++t) {
    int r = by * 32 + threadIdx.y + t * 8;
    tile[threadIdx.y + t * 8][threadIdx.x] = src[(size_t)r * CN + c];
  }
  __syncthreads();
  const int dc = by * 32 + threadIdx.x;  // RK index (contiguous in dst)
#pragma unroll
  for (int t = 0; t < 4; ++t) {
    int dr = bx * 32 + threadIdx.y + t * 8;  // CN index
    dst[(size_t)dr * RK + dc] = f2bf(tile[threadIdx.x][threadIdx.y + t * 8]);
  }
}

// ---------- fp32 -> bf16 bulk convert (8 elems/thread) ----------
__global__ __launch_bounds__(256) void cvt_bf16(const float* __restrict__ src,
                                                ushort_t* __restrict__ dst) {
  size_t i = ((size_t)blockIdx.x * 256 + threadIdx.x) * 8;
  float4 a = *(const float4*)(src + i);
  float4 b = *(const float4*)(src + i + 4);
  uint4 o;
  o.x = (uint32)f2bf(a.x) | ((uint32)f2bf(a.y) << 16);
  o.y = (uint32)f2bf(a.z) | ((uint32)f2bf(a.w) << 16);
  o.z = (uint32)f2bf(b.x) | ((uint32)f2bf(b.y) << 16);
  o.w = (uint32)f2bf(b.z) | ((uint32)f2bf(b.w) << 16);
  *(uint4*)(dst + i) = o;
}

// ---------- GEMM: C(M,N) = A(M,K) @ Bt(N,K)^T, bf16 in, fused epilogues ----------
// 128x128 tile, BK=32, 4 waves (2x2 of 64x64), 16x16x32 MFMA, 4x4 acc tiles/wave.
__global__ __launch_bounds__(256) void gemm_bt(
    const ushort_t* __restrict__ A, int lda,
    const ushort_t* __restrict__ Bt, int K,
    void* __restrict__ outp, int ldo, int mode,
    const float* __restrict__ bias,
    const float* __restrict__ gw1, const float* __restrict__ nw1,
    const float* __restrict__ gb1, const float* __restrict__ nb1,
    const float* __restrict__ bboxes) {
  __shared__ ushort_t sA[128 * 32];
  __shared__ ushort_t sB[128 * 32];
  const int tid = threadIdx.x;
  const int w = tid >> 6, l = tid & 63;
  const int wm = (w >> 1) * 64, wn = (w & 1) * 64;
  const int lr = l >> 4, lc = l & 15;
  const int mBase = blockIdx.y * 128, cBase = blockIdx.x * 128;

  // staging map: thread t -> row t/4, col8 (t%4)*8 ; LDS offset = t*16B (contiguous)
  const int r0 = tid >> 2;
  const int c8 = (tid & 3) * 8;
  const ushort_t* gA = A + (size_t)(mBase + r0) * lda + c8;
  const ushort_t* gB = Bt + (size_t)(cBase + r0) * K + c8;
  const size_t sA64 = (size_t)64 * lda;
  const size_t sB64 = (size_t)64 * K;
  char* ldsA0 = (char*)sA + w * 1024;          // wave-uniform bases
  char* ldsA1 = (char*)sA + 4096 + w * 1024;
  char* ldsB0 = (char*)sB + w * 1024;
  char* ldsB1 = (char*)sB + 4096 + w * 1024;

  f32x4 acc[4][4] = {};

  for (int k0 = 0; k0 < K; k0 += 32) {
    gl_lds16(gA + k0, ldsA0);
    gl_lds16(gA + sA64 + k0, ldsA1);
    gl_lds16(gB + k0, ldsB0);
    gl_lds16(gB + sB64 + k0, ldsB1);
    __syncthreads();
    bf16x8 af[4], bfr[4];
#pragma unroll
    for (int i = 0; i < 4; ++i)
      af[i] = *(const bf16x8*)&sA[(wm + i * 16 + lc) * 32 + lr * 8];
#pragma unroll
    for (int j = 0; j < 4; ++j)
      bfr[j] = *(const bf16x8*)&sB[(wn + j * 16 + lc) * 32 + lr * 8];
#pragma unroll
    for (int i = 0; i < 4; ++i)
#pragma unroll
      for (int j = 0; j < 4; ++j)
        acc[i][j] = __builtin_amdgcn_mfma_f32_16x16x32_bf16(af[i], bfr[j], acc[i][j], 0, 0, 0);
    __syncthreads();
  }

  // C/D layout: col = lane&15, row = (lane>>4)*4 + e
  if (mode == 1) {
    // out = relu(acc + b1[col] + 0.1 * sum_j s5[row][j] * W1[2048+j][col]) -> bf16, ldo=4096
    const bool gate = (cBase < 2048);
    const float* b1 = gate ? gb1 : nb1;
    const float* wsrc = gate ? gw1 : nw1;
    const int coffs = gate ? 0 : 2048;
    float bcol[4], w5[4][5];
#pragma unroll
    for (int j = 0; j < 4; ++j) {
      int c = cBase + wn + j * 16 + lc - coffs;
      bcol[j] = b1[c];
#pragma unroll
      for (int t = 0; t < 5; ++t) w5[j][t] = wsrc[(size_t)(2048 + t) * 2048 + c];
    }
    ushort_t* O = (ushort_t*)outp;
#pragma unroll
    for (int i = 0; i < 4; ++i)
#pragma unroll
      for (int e = 0; e < 4; ++e) {
        size_t rg = mBase + wm + i * 16 + lr * 4 + e;
        const float* bb = bboxes + rg * 4;
        float s0 = bb[0], s1 = bb[1], s2 = bb[2], s3 = bb[3];
        float s4 = (s2 - s0) * (s3 - s1);
#pragma unroll
        for (int j = 0; j < 4; ++j) {
          float corr = 0.1f * (s0 * w5[j][0] + s1 * w5[j][1] + s2 * w5[j][2] +
                               s3 * w5[j][3] + s4 * w5[j][4]);
          float v = acc[i][j][e] + bcol[j] + corr;
          v = v > 0.f ? v : 0.f;
          O[rg * ldo + (cBase + wn + j * 16 + lc)] = f2bf(v);
        }
      }
  } else {
    float bcol[4];
#pragma unroll
    for (int j = 0; j < 4; ++j) bcol[j] = bias[cBase + wn + j * 16 + lc];
    if (mode == 4) {  // fp32 out, no relu
      float* O = (float*)outp;
#pragma unroll
      for (int i = 0; i < 4; ++i)
#pragma unroll
        for (int e = 0; e < 4; ++e) {
          size_t rg = mBase + wm + i * 16 + lr * 4 + e;
#pragma unroll
          for (int j = 0; j < 4; ++j)
            O[rg * ldo + (cBase + wn + j * 16 + lc)] = acc[i][j][e] + bcol[j];
        }
    } else {  // bf16 out; mode 3 applies relu
      const bool do_relu = (mode == 3);
      ushort_t* O = (ushort_t*)outp;
#pragma unroll
      for (int i = 0; i < 4; ++i)
#pragma unroll
        for (int e = 0; e < 4; ++e) {
          size_t rg = mBase + wm + i * 16 + lr * 4 + e;
#pragma unroll
          for (int j = 0; j < 4; ++j) {
            float v = acc[i][j][e] + bcol[j];
            if (do_relu && v < 0.f) v = 0.f;
            O[rg * ldo + (cBase + wn + j * 16 + lc)] = f2bf(v);
          }
        }
    }
  }
}

// ---------- gate layer 2: m = sigmoid(h_gate . gw2 + gb2) ----------
__global__ __launch_bounds__(256) void gate2_k(const ushort_t* __restrict__ hcat,
                                               const float* __restrict__ gw2,
                                               const float* __restrict__ gb2,
                                               float* __restrict__ msig) {
  __shared__ float sred[4];
  const int row = blockIdx.x;
  const int d0 = threadIdx.x * 8;  // 256*8 = 2048
  uint4 u = *(const uint4*)(hcat + (size_t)row * 4096 + d0);
  float4 w0 = *(const float4*)(gw2 + d0);
  float4 w1 = *(const float4*)(gw2 + d0 + 4);
  float s = bflo(u.x) * w0.x + bfhi(u.x) * w0.y + bflo(u.y) * w0.z + bfhi(u.y) * w0.w +
            bflo(u.z) * w1.x + bfhi(u.z) * w1.y + bflo(u.w) * w1.z + bfhi(u.w) * w1.w;
  float tot = blk_sum(s, sred);
  if (threadIdx.x == 0) msig[row] = 1.f / (1.f + expf(-(tot + gb2[0])));
}

// ---------- top-P gather + weighted sum + l2norm + residual ----------
__global__ __launch_bounds__(256) void aggregate_k(const float* __restrict__ img_range,
                                                   const float* __restrict__ msig,
                                                   const ushort_t* __restrict__ vbf,
                                                   const float* __restrict__ images,
                                                   ushort_t* __restrict__ imgs_out) {
  __shared__ int s_id[5];
  __shared__ float s_w[5];
  __shared__ float sred[4];
  const int row = blockIdx.x;
  const int b = row / 36, k = row - b * 36;
  const int tid = threadIdx.x;
  if (tid < 64) {  // whole wave 0
    float val = (tid < 36) ? img_range[(size_t)row * 36 + tid] : 0.f;
    unsigned long long mask = __ballot(val == 1.0f);
    if (tid < 5) {
      // tid-th lowest set bit, else self index k  (== jax stable top_k + where)
      unsigned long long mm = mask;
      for (int p = 0; p < tid; ++p) mm &= (mm - 1);
      int id = mm ? (int)__builtin_ctzll(mm) : k;
      s_id[tid] = id;
      s_w[tid] = msig[b * 36 + id];
    }
  }
  __syncthreads();
  const int d0 = tid * 8;
  float acc8[8] = {0, 0, 0, 0, 0, 0, 0, 0};
#pragma unroll
  for (int p = 0; p < 5; ++p) {
    uint4 u = *(const uint4*)(vbf + ((size_t)(b * 36 + s_id[p])) * 2048 + d0);
    float wg = s_w[p];
    acc8[0] += wg * bflo(u.x); acc8[1] += wg * bfhi(u.x);
    acc8[2] += wg * bflo(u.y); acc8[3] += wg * bfhi(u.y);
    acc8[4] += wg * bflo(u.z); acc8[5] += wg * bfhi(u.z);
    acc8[6] += wg * bflo(u.w); acc8[7] += wg * bfhi(u.w);
  }
  float ss = 0;
#pragma unroll
  for (int e = 0; e < 8; ++e) ss += acc8[e] * acc8[e];
  float tot = blk_sum(ss, sred);
  float inv = 1.f / (sqrtf(tot) + 1e-8f);
  const float* im = images + (size_t)row * 2048 + d0;
  float4 x0 = *(const float4*)im;
  float4 x1 = *(const float4*)(im + 4);
  float r[8] = {x0.x + acc8[0] * inv, x0.y + acc8[1] * inv, x0.z + acc8[2] * inv,
                x0.w + acc8[3] * inv, x1.x + acc8[4] * inv, x1.y + acc8[5] * inv,
                x1.z + acc8[6] * inv, x1.w + acc8[7] * inv};
  uint4 o;
  o.x = (uint32)f2bf(r[0]) | ((uint32)f2bf(r[1]) << 16);
  o.y = (uint32)f2bf(r[2]) | ((uint32)f2bf(r[3]) << 16);
  o.z = (uint32)f2bf(r[4]) | ((uint32)f2bf(r[5]) << 16);
  o.w = (uint32)f2bf(r[6]) | ((uint32)f2bf(r[7]) << 16);
  *(uint4*)(imgs_out + (size_t)row * 2048 + d0) = o;
}

// ---------- final l2norm over E=1024 ----------
__global__ __launch_bounds__(256) void l2norm_k(const float* __restrict__ emb,
                                                float* __restrict__ out) {
  __shared__ float sred[4];
  size_t base = (size_t)blockIdx.x * 1024 + threadIdx.x * 4;
  float4 x = *(const float4*)(emb + base);
  float tot = blk_sum(x.x * x.x + x.y * x.y + x.z * x.z + x.w * x.w, sred);
  float inv = 1.f / (sqrtf(tot) + 1e-8f);
  float4 o = {x.x * inv, x.y * inv, x.z * inv, x.w * inv};
  *(float4*)(out + base) = o;
}

extern "C" void kernel_launch(void* const* d_in, const int* in_sizes, int n_in,
                              void* d_out, int out_size, void* d_ws, size_t ws_size,
                              hipStream_t stream) {
  (void)in_sizes; (void)n_in; (void)out_size; (void)ws_size;
  const float* images    = (const float*)d_in[0];
  const float* bboxes    = (const float*)d_in[1];
  const float* img_range = (const float*)d_in[2];
  const float* gate_w1   = (const float*)d_in[3];
  const float* gate_b1   = (const float*)d_in[4];
  const float* gate_w2   = (const float*)d_in[5];
  const float* gate_b2   = (const float*)d_in[6];
  const float* node_w1   = (const float*)d_in[7];
  const float* node_b1   = (const float*)d_in[8];
  const float* node_w2   = (const float*)d_in[9];
  const float* node_b2   = (const float*)d_in[10];
  const float* map_w1    = (const float*)d_in[11];
  const float* map_b1    = (const float*)d_in[12];
  const float* map_w2    = (const float*)d_in[13];
  const float* map_b2    = (const float*)d_in[14];

  char* ws = (char*)d_ws;
  size_t off = 0;
  auto take = [&](size_t bytes) {
    char* p = ws + off;
    off += (bytes + 255) & ~(size_t)255;
    return p;
  };
  ushort_t* W1t  = (ushort_t*)take((size_t)4096 * 2048 * 2);  // [gate|node]_w1^T
  ushort_t* W2t  = (ushort_t*)take((size_t)2048 * 2048 * 2);  // node_w2^T
  ushort_t* W3t  = (ushort_t*)take((size_t)2048 * 2048 * 2);  // map_w1^T
  ushort_t* W4t  = (ushort_t*)take((size_t)1024 * 2048 * 2);  // map_w2^T
  ushort_t* Abuf = (ushort_t*)take((size_t)9216 * 2048 * 2);  // images_bf16 -> imgs_bf16
  ushort_t* Hcat = (ushort_t*)take((size_t)9216 * 4096 * 2);  // h_cat -> emb(fp32)
  ushort_t* Vbuf = (ushort_t*)take((size_t)9216 * 2048 * 2);  // v_bf16 -> h3
  float*    Msig = (float*)take((size_t)9216 * 4);
  float*    Emb  = (float*)Hcat;

  dim3 tb(32, 8);
  transpose_bf16<<<dim3(64, 64), tb, 0, stream>>>(gate_w1, W1t, 2048, 2048);
  transpose_bf16<<<dim3(64, 64), tb, 0, stream>>>(node_w1, W1t + (size_t)2048 * 2048, 2048, 2048);
  transpose_bf16<<<dim3(64, 64), tb, 0, stream>>>(node_w2, W2t, 2048, 2048);
  transpose_bf16<<<dim3(64, 64), tb, 0, stream>>>(map_w1, W3t, 2048, 2048);
  transpose_bf16<<<dim3(32, 64), tb, 0, stream>>>(map_w2, W4t, 2048, 1024);
  cvt_bf16<<<9216, 256, 0, stream>>>(images, Abuf);

  // G1: (9216 x 2048) @ (2048 x 4096) + bias + bbox corr, relu
  gemm_bt<<<dim3(32, 72), 256, 0, stream>>>(Abuf, 2048, W1t, 2048, Hcat, 4096, 1,
                                            nullptr, gate_w1, node_w1, gate_b1, node_b1, bboxes);
  gate2_k<<<9216, 256, 0, stream>>>(Hcat, gate_w2, gate_b2, Msig);
  // G2: node hidden @ node_w2 + node_b2 -> V
  gemm_bt<<<dim3(16, 72), 256, 0, stream>>>(Hcat + 2048, 4096, W2t, 2048, Vbuf, 2048, 2,
                                            node_b2, nullptr, nullptr, nullptr, nullptr, nullptr);
  aggregate_k<<<9216, 256, 0, stream>>>(img_range, Msig, Vbuf, images, Abuf);
  // G3: imgs @ map_w1 + map_b1, relu -> H3 (reuse Vbuf)
  gemm_bt<<<dim3(16, 72), 256, 0, stream>>>(Abuf, 2048, W3t, 2048, Vbuf, 2048, 3,
                                            map_b1, nullptr, nullptr, nullptr, nullptr, nullptr);
  // G4: H3 @ map_w2 + map_b2 -> emb fp32 (reuse Hcat)
  gemm_bt<<<dim3(8, 72), 256, 0, stream>>>(Vbuf, 2048, W4t, 2048, Emb, 1024, 4,
                                           map_b2, nullptr, nullptr, nullptr, nullptr, nullptr);
  l2norm_k<<<9216, 256, 0, stream>>>(Emb, (float*)d_out);
}